// Round 2
// baseline (1723.644 us; speedup 1.0000x reference)
//
#include <hip/hip_runtime.h>
#include <hip/hip_bf16.h>
#include <cstddef>

#define N_NODES 50000
#define N_EDGES 800000
#define MP      50048      // 64-row padded node count (782*64)
#define SCALE   0.25f      // HD^-0.5, HD=16
#define LN_EPS  1e-5f

// ---------------------------------------------------------------- LayerNorm
__global__ __launch_bounds__(256) void ln_kernel(
    const float* __restrict__ x, const float* __restrict__ g,
    const float* __restrict__ b, float* __restrict__ y, int n)
{
    int row = blockIdx.x * 4 + (threadIdx.x >> 6);
    if (row >= n) return;
    int lane = threadIdx.x & 63;
    float2 v = *(const float2*)&x[(size_t)row * 128 + lane * 2];
    float s  = v.x + v.y;
    float ss = v.x * v.x + v.y * v.y;
    #pragma unroll
    for (int m = 1; m < 64; m <<= 1) {
        s  += __shfl_xor(s, m);
        ss += __shfl_xor(ss, m);
    }
    float mu  = s * (1.0f / 128.0f);
    float var = ss * (1.0f / 128.0f) - mu * mu;
    float inv = rsqrtf(var + LN_EPS);
    float2 gg = *(const float2*)&g[lane * 2];
    float2 bb = *(const float2*)&b[lane * 2];
    float2 o;
    o.x = (v.x - mu) * inv * gg.x + bb.x;
    o.y = (v.y - mu) * inv * gg.y + bb.y;
    *(float2*)&y[(size_t)row * 128 + lane * 2] = o;
}

// ------------------------------------------------------ edge bias: ef @ We + be
__global__ __launch_bounds__(256) void ebias_kernel(
    const float* __restrict__ ef, const float* __restrict__ We,
    const float* __restrict__ be, float* __restrict__ eb, int nE)
{
    int wid  = threadIdx.x >> 6;
    int lane = threadIdx.x & 63;
    float w0[8], w1[8], beh[8];
    #pragma unroll
    for (int h = 0; h < 8; h++) {
        w0[h]  = We[(2 * lane) * 8 + h];
        w1[h]  = We[(2 * lane + 1) * 8 + h];
        beh[h] = be[h];
    }
    for (int e = blockIdx.x * 4 + wid; e < nE; e += gridDim.x * 4) {
        float2 v = *(const float2*)&ef[(size_t)e * 128 + lane * 2];
        float acc[8];
        #pragma unroll
        for (int h = 0; h < 8; h++) acc[h] = v.x * w0[h] + v.y * w1[h];
        #pragma unroll
        for (int m = 1; m < 64; m <<= 1) {
            #pragma unroll
            for (int h = 0; h < 8; h++) acc[h] += __shfl_xor(acc[h], m);
        }
        if (lane == 0) {
            #pragma unroll
            for (int h = 0; h < 8; h++)
                eb[(size_t)e * 8 + h] = acc[h] + beh[h];
        }
    }
}

// ---------------------------------------------------------------- CSR build
__global__ __launch_bounds__(256) void hist_kernel(
    const int* __restrict__ dst, int* __restrict__ cnt, int n)
{
    int i = blockIdx.x * 256 + threadIdx.x;
    if (i < n) atomicAdd(&cnt[dst[i]], 1);
}

__global__ __launch_bounds__(1024) void scan_kernel(
    const int* __restrict__ cnt, int* __restrict__ offs, int n)
{
    __shared__ int lds[1024];
    int t = threadIdx.x;
    const int C = (n + 1023) >> 10;
    int base = t * C;
    int s = 0;
    for (int i = 0; i < C; i++) {
        int idx = base + i;
        if (idx < n) s += cnt[idx];
    }
    lds[t] = s;
    __syncthreads();
    for (int off = 1; off < 1024; off <<= 1) {
        int v = (t >= off) ? lds[t - off] : 0;
        __syncthreads();
        lds[t] += v;
        __syncthreads();
    }
    int run = lds[t] - s;   // exclusive prefix of this thread's chunk
    if (t == 0) offs[0] = 0;
    for (int i = 0; i < C; i++) {
        int idx = base + i;
        if (idx < n) { run += cnt[idx]; offs[idx + 1] = run; }
    }
}

__global__ __launch_bounds__(256) void scatter_kernel(
    const int* __restrict__ dst, const int* __restrict__ offs,
    int* __restrict__ cur, int* __restrict__ perm, int n)
{
    int i = blockIdx.x * 256 + threadIdx.x;
    if (i < n) {
        int d = dst[i];
        int p = offs[d] + atomicAdd(&cur[d], 1);
        perm[p] = i;
    }
}

// ------------------------------------------------- attention (wave per dst node)
__global__ __launch_bounds__(256) void attn_kernel(
    const float* __restrict__ qkv, const float* __restrict__ eb,
    const int* __restrict__ offs, const int* __restrict__ perm,
    const int* __restrict__ srcA, float* __restrict__ attn, int n)
{
    int node = blockIdx.x * 4 + (threadIdx.x >> 6);
    if (node >= n) return;
    int lane = threadIdx.x & 63;
    int d0 = lane * 2;
    int hd = lane >> 3;                 // head index for both dims
    float2 q = *(const float2*)&qkv[(size_t)node * 384 + d0];
    float m = -3.0e38f, ssum = 0.f, a0 = 0.f, a1 = 0.f;
    int beg = offs[node], end = offs[node + 1];
    for (int i = beg; i < end; i++) {
        int e = perm[i];
        int s = srcA[e];
        float2 k = *(const float2*)&qkv[(size_t)s * 384 + 128 + d0];
        float p = q.x * k.x + q.y * k.y;
        p += __shfl_xor(p, 1);
        p += __shfl_xor(p, 2);
        p += __shfl_xor(p, 4);
        float score = p * SCALE + eb[(size_t)e * 8 + hd];
        float mn = fmaxf(m, score);
        float sc = __expf(m - mn);
        float a  = __expf(score - mn);
        float2 v = *(const float2*)&qkv[(size_t)s * 384 + 256 + d0];
        ssum = ssum * sc + a;
        a0 = a0 * sc + a * v.x;
        a1 = a1 * sc + a * v.y;
        m = mn;
    }
    float inv = (ssum > 0.f) ? 1.0f / ssum : 0.0f;
    float2 o; o.x = a0 * inv; o.y = a1 * inv;
    *(float2*)&attn[(size_t)node * 128 + d0] = o;
}

// ---------------------------------------------------------------- fp32 GEMM
#define TM 64
#define TN 64
#define TK 32

__device__ __forceinline__ void gemm_body(
    const float* __restrict__ A, int lda,
    const float* __restrict__ B, int ldb,
    const float* __restrict__ bias,
    const float* __restrict__ res, int ldr,
    float* __restrict__ C, int ldc,
    int K, int Mstore, bool relu)
{
    __shared__ float As[TM][TK + 1];
    __shared__ float Bs[TK][TN];
    const int tid = threadIdx.x;
    const int tx = tid & 15, ty = tid >> 4;
    const int row0 = blockIdx.x * TM;
    float acc[4][4] = {};

    for (int k0 = 0; k0 < K; k0 += TK) {
        {   // A tile: 64x32, two passes of 32 rows
            int r = tid >> 3, c = (tid & 7) * 4;
            float4 a0 = *(const float4*)&A[(size_t)(row0 + r) * lda + k0 + c];
            As[r][c] = a0.x; As[r][c + 1] = a0.y; As[r][c + 2] = a0.z; As[r][c + 3] = a0.w;
            float4 a1 = *(const float4*)&A[(size_t)(row0 + r + 32) * lda + k0 + c];
            As[r + 32][c] = a1.x; As[r + 32][c + 1] = a1.y; As[r + 32][c + 2] = a1.z; As[r + 32][c + 3] = a1.w;
        }
        {   // B tile: 32x64, two passes of 16 rows
            int r = tid >> 4, c = (tid & 15) * 4;
            *(float4*)&Bs[r][c]      = *(const float4*)&B[(size_t)(k0 + r) * ldb + c];
            *(float4*)&Bs[r + 16][c] = *(const float4*)&B[(size_t)(k0 + r + 16) * ldb + c];
        }
        __syncthreads();
        #pragma unroll
        for (int kk = 0; kk < TK; kk++) {
            float a_[4];
            #pragma unroll
            for (int i = 0; i < 4; i++) a_[i] = As[ty * 4 + i][kk];
            float4 b4 = *(const float4*)&Bs[kk][tx * 4];
            float b_[4] = { b4.x, b4.y, b4.z, b4.w };
            #pragma unroll
            for (int i = 0; i < 4; i++)
                #pragma unroll
                for (int j = 0; j < 4; j++)
                    acc[i][j] += a_[i] * b_[j];
        }
        __syncthreads();
    }

    float4 bias4 = *(const float4*)&bias[tx * 4];
    #pragma unroll
    for (int i = 0; i < 4; i++) {
        int row = row0 + ty * 4 + i;
        if (row < Mstore) {
            float4 o;
            o.x = acc[i][0] + bias4.x;
            o.y = acc[i][1] + bias4.y;
            o.z = acc[i][2] + bias4.z;
            o.w = acc[i][3] + bias4.w;
            if (res) {
                float4 r4 = *(const float4*)&res[(size_t)row * ldr + tx * 4];
                o.x += r4.x; o.y += r4.y; o.z += r4.z; o.w += r4.w;
            }
            if (relu) {
                o.x = fmaxf(o.x, 0.f); o.y = fmaxf(o.y, 0.f);
                o.z = fmaxf(o.z, 0.f); o.w = fmaxf(o.w, 0.f);
            }
            *(float4*)&C[(size_t)row * ldc + tx * 4] = o;
        }
    }
}

__global__ __launch_bounds__(256) void gemm_generic(
    const float* __restrict__ A, int lda,
    const float* __restrict__ B, int ldb,
    const float* __restrict__ bias,
    const float* __restrict__ res, int ldr,
    float* __restrict__ C, int ldc,
    int K, int Mstore, int relu)
{
    int col0 = blockIdx.y * TN;
    gemm_body(A, lda, B + col0, ldb, bias + col0,
              res ? res + col0 : nullptr, ldr, C + col0, ldc, K, Mstore, relu != 0);
}

__global__ __launch_bounds__(256) void gemm_qkv(
    const float* __restrict__ A,
    const float* __restrict__ Wq, const float* __restrict__ Wk, const float* __restrict__ Wv,
    const float* __restrict__ bq, const float* __restrict__ bk, const float* __restrict__ bv,
    float* __restrict__ QKV)
{
    int sel = blockIdx.y >> 1;
    int cl  = (blockIdx.y & 1) * TN;
    const float* B    = (sel == 0 ? Wq : sel == 1 ? Wk : Wv) + cl;
    const float* bias = (sel == 0 ? bq : sel == 1 ? bk : bv) + cl;
    float* C = QKV + sel * 128 + cl;
    gemm_body(A, 128, B, 128, bias, nullptr, 0, C, 384, 128, MP, false);
}

// ---------------------------------------------------------------- launcher
extern "C" void kernel_launch(void* const* d_in, const int* in_sizes, int n_in,
                              void* d_out, int out_size, void* d_ws, size_t ws_size,
                              hipStream_t stream)
{
    (void)in_sizes; (void)n_in; (void)out_size; (void)ws_size;
    const float* h    = (const float*)d_in[0];
    const int*   src  = (const int*)d_in[1];
    const int*   dst  = (const int*)d_in[2];
    const float* ef   = (const float*)d_in[3];
    const float* Wq   = (const float*)d_in[4];
    const float* bq   = (const float*)d_in[5];
    const float* Wk   = (const float*)d_in[6];
    const float* bk   = (const float*)d_in[7];
    const float* Wv   = (const float*)d_in[8];
    const float* bv   = (const float*)d_in[9];
    const float* We   = (const float*)d_in[10];
    const float* be   = (const float*)d_in[11];
    const float* Wo   = (const float*)d_in[12];
    const float* bo   = (const float*)d_in[13];
    const float* g1   = (const float*)d_in[14];
    const float* b1   = (const float*)d_in[15];
    const float* g2   = (const float*)d_in[16];
    const float* b2l  = (const float*)d_in[17];
    const float* W1   = (const float*)d_in[18];
    const float* b1f  = (const float*)d_in[19];
    const float* W2   = (const float*)d_in[20];
    const float* b2f  = (const float*)d_in[21];
    float* out = (float*)d_out;

    char* ws = (char*)d_ws;
    float* hc   = (float*)ws;  ws += (size_t)MP * 128 * 4;
    float* qkv  = (float*)ws;  ws += (size_t)MP * 384 * 4;
    float* attn = (float*)ws;  ws += (size_t)MP * 128 * 4;
    float* eb   = (float*)ws;  ws += (size_t)N_EDGES * 8 * 4;
    int*   offs = (int*)ws;    ws += ((N_NODES + 1) * 4 + 252) / 256 * 256;
    int*   cnt  = (int*)ws;    ws += ((size_t)N_NODES * 4 + 252) / 256 * 256;
    int*   perm = (int*)ws;    ws += (size_t)N_EDGES * 4;
    float* mid  = qkv;   // reuse for FFN hidden  (MP x 256 fits in MP x 384)
    float* hn   = attn;  // reuse for LN2 output

    const int rowBlocks = MP / TM;  // 782

    // prologue: LN1, edge bias, CSR
    ln_kernel<<<N_NODES / 4, 256, 0, stream>>>(h, g1, b1, hc, N_NODES);
    ebias_kernel<<<2048, 256, 0, stream>>>(ef, We, be, eb, N_EDGES);
    hipMemsetAsync(cnt, 0, N_NODES * 4, stream);
    hist_kernel<<<(N_EDGES + 255) / 256, 256, 0, stream>>>(dst, cnt, N_EDGES);
    scan_kernel<<<1, 1024, 0, stream>>>(cnt, offs, N_NODES);
    hipMemsetAsync(cnt, 0, N_NODES * 4, stream);
    scatter_kernel<<<(N_EDGES + 255) / 256, 256, 0, stream>>>(dst, offs, cnt, perm, N_EDGES);

    // 2 hops
    for (int hop = 0; hop < 2; hop++) {
        gemm_qkv<<<dim3(rowBlocks, 6), 256, 0, stream>>>(hc, Wq, Wk, Wv, bq, bk, bv, qkv);
        attn_kernel<<<N_NODES / 4, 256, 0, stream>>>(qkv, eb, offs, perm, src, attn, N_NODES);
        gemm_generic<<<dim3(rowBlocks, 2), 256, 0, stream>>>(
            attn, 128, Wo, 128, bo, hc, 128, hc, 128, 128, MP, 0);
    }

    // FFN
    ln_kernel<<<N_NODES / 4, 256, 0, stream>>>(hc, g2, b2l, hn, N_NODES);
    gemm_generic<<<dim3(rowBlocks, 4), 256, 0, stream>>>(
        hn, 128, W1, 256, b1f, nullptr, 0, mid, 256, 128, MP, 1);
    gemm_generic<<<dim3(rowBlocks, 2), 256, 0, stream>>>(
        mid, 256, W2, 128, b2f, hc, 128, out, 128, 256, N_NODES, 0);
}

// Round 5
// 1454.053 us; speedup vs baseline: 1.1854x; 1.1854x over previous
//
#include <hip/hip_runtime.h>
#include <hip/hip_bf16.h>
#include <cstddef>

#define N_NODES 50000
#define N_EDGES 800000
#define MP      50048      // 64-row padded node count (782*64)
#define SCALE   0.25f      // HD^-0.5, HD=16
#define LN_EPS  1e-5f

typedef __attribute__((ext_vector_type(8))) short short8;
typedef __attribute__((ext_vector_type(4))) float f32x4;

// float -> bf16 bits, round-to-nearest-even (bitwise, no API dependency)
__device__ __forceinline__ unsigned short f2bu(float f) {
    unsigned int u = __float_as_uint(f);
    unsigned int r = (u + 0x7FFFu + ((u >> 16) & 1u)) >> 16;
    return (unsigned short)r;
}

// ---------------------------------------------------------------- LayerNorm
// writes fp32 copy (nullable) and bf16 copy (nullable)
__global__ __launch_bounds__(256) void ln_kernel(
    const float* __restrict__ x, const float* __restrict__ g,
    const float* __restrict__ b, float* __restrict__ yf,
    unsigned short* __restrict__ yb, int n)
{
    int row = blockIdx.x * 4 + (threadIdx.x >> 6);
    if (row >= n) return;
    int lane = threadIdx.x & 63;
    float2 v = *(const float2*)&x[(size_t)row * 128 + lane * 2];
    float s  = v.x + v.y;
    float ss = v.x * v.x + v.y * v.y;
    #pragma unroll
    for (int m = 1; m < 64; m <<= 1) {
        s  += __shfl_xor(s, m);
        ss += __shfl_xor(ss, m);
    }
    float mu  = s * (1.0f / 128.0f);
    float var = ss * (1.0f / 128.0f) - mu * mu;
    float inv = rsqrtf(var + LN_EPS);
    float2 gg = *(const float2*)&g[lane * 2];
    float2 bb = *(const float2*)&b[lane * 2];
    float2 o;
    o.x = (v.x - mu) * inv * gg.x + bb.x;
    o.y = (v.y - mu) * inv * gg.y + bb.y;
    if (yf) *(float2*)&yf[(size_t)row * 128 + lane * 2] = o;
    if (yb) {
        ushort2 ob; ob.x = f2bu(o.x); ob.y = f2bu(o.y);
        *(ushort2*)&yb[(size_t)row * 128 + lane * 2] = ob;
    }
}

// ------------------------------------------------------ edge bias: ef @ We + be
// lane = (slice s = lane>>3, head h = lane&7): 16-dim partial dot per lane,
// then 3 shfl_xor to sum the 8 slices. One wave = one edge row (512B).
__global__ __launch_bounds__(256) void ebias_kernel(
    const float* __restrict__ ef, const float* __restrict__ We,
    const float* __restrict__ be, float* __restrict__ eb, int nE)
{
    int wid  = threadIdx.x >> 6;
    int lane = threadIdx.x & 63;
    int s = lane >> 3;
    int h = lane & 7;
    float w[16];
    #pragma unroll
    for (int i = 0; i < 16; i++) w[i] = We[(s * 16 + i) * 8 + h];
    float beh = be[h];
    int stride = gridDim.x * 4;
    for (int e = blockIdx.x * 4 + wid; e < nE; e += stride) {
        const float* base = &ef[(size_t)e * 128 + s * 16];
        float4 v0 = *(const float4*)(base);
        float4 v1 = *(const float4*)(base + 4);
        float4 v2 = *(const float4*)(base + 8);
        float4 v3 = *(const float4*)(base + 12);
        float acc = v0.x * w[0]  + v0.y * w[1]  + v0.z * w[2]  + v0.w * w[3]
                  + v1.x * w[4]  + v1.y * w[5]  + v1.z * w[6]  + v1.w * w[7]
                  + v2.x * w[8]  + v2.y * w[9]  + v2.z * w[10] + v2.w * w[11]
                  + v3.x * w[12] + v3.y * w[13] + v3.z * w[14] + v3.w * w[15];
        acc += __shfl_xor(acc, 8);
        acc += __shfl_xor(acc, 16);
        acc += __shfl_xor(acc, 32);
        if (lane < 8) eb[(size_t)e * 8 + lane] = acc + beh;
    }
}

// ------------------------------------------- weight prep: transpose + bf16
// WqkvT[3][128][128], WoT[128][128], W1T[256][128], W2T[128][256]; T[n][k]=W[k][n]
__global__ __launch_bounds__(256) void prep_weights(
    const float* __restrict__ Wq, const float* __restrict__ Wk,
    const float* __restrict__ Wv, const float* __restrict__ Wo,
    const float* __restrict__ W1, const float* __restrict__ W2,
    unsigned short* __restrict__ WqkvT, unsigned short* __restrict__ WoT,
    unsigned short* __restrict__ W1T, unsigned short* __restrict__ W2T)
{
    int i = blockIdx.x * 256 + threadIdx.x;
    if (i < 49152) {
        int s = i >> 14, r = i & 16383;
        int n = r >> 7, k = r & 127;
        const float* W = s == 0 ? Wq : s == 1 ? Wk : Wv;
        WqkvT[i] = f2bu(W[k * 128 + n]);
    } else if (i < 65536) {
        int r = i - 49152; int n = r >> 7, k = r & 127;
        WoT[r] = f2bu(Wo[k * 128 + n]);
    } else if (i < 98304) {
        int r = i - 65536; int n = r >> 7, k = r & 127;     // W1T[256][128]
        W1T[r] = f2bu(W1[k * 256 + n]);
    } else if (i < 131072) {
        int r = i - 98304; int n = r >> 8, k = r & 255;     // W2T[128][256]
        W2T[r] = f2bu(W2[k * 128 + n]);
    }
}

// ---------------------------------------------------------------- CSR build
__global__ __launch_bounds__(256) void hist_kernel(
    const int* __restrict__ dst, int* __restrict__ cnt, int n)
{
    int i = blockIdx.x * 256 + threadIdx.x;
    if (i < n) atomicAdd(&cnt[dst[i]], 1);
}

__global__ __launch_bounds__(1024) void scan_kernel(
    const int* __restrict__ cnt, int* __restrict__ offs, int n)
{
    __shared__ int lds[1024];
    int t = threadIdx.x;
    const int C = (n + 1023) >> 10;
    int base = t * C;
    int s = 0;
    for (int i = 0; i < C; i++) {
        int idx = base + i;
        if (idx < n) s += cnt[idx];
    }
    lds[t] = s;
    __syncthreads();
    for (int off = 1; off < 1024; off <<= 1) {
        int v = (t >= off) ? lds[t - off] : 0;
        __syncthreads();
        lds[t] += v;
        __syncthreads();
    }
    int run = lds[t] - s;   // exclusive prefix of this thread's chunk
    if (t == 0) offs[0] = 0;
    for (int i = 0; i < C; i++) {
        int idx = base + i;
        if (idx < n) { run += cnt[idx]; offs[idx + 1] = run; }
    }
}

__global__ __launch_bounds__(256) void scatter_kernel(
    const int* __restrict__ dst, const int* __restrict__ offs,
    int* __restrict__ cur, int* __restrict__ perm, int n)
{
    int i = blockIdx.x * 256 + threadIdx.x;
    if (i < n) {
        int d = dst[i];
        int p = offs[d] + atomicAdd(&cur[d], 1);
        perm[p] = i;
    }
}

// ------------------------------------------------- attention (wave per dst node)
// reads fp32 qkv, writes bf16 output (A-operand of the Wo GEMM)
__global__ __launch_bounds__(256) void attn_kernel(
    const float* __restrict__ qkv, const float* __restrict__ eb,
    const int* __restrict__ offs, const int* __restrict__ perm,
    const int* __restrict__ srcA, unsigned short* __restrict__ attnb, int n)
{
    int node = blockIdx.x * 4 + (threadIdx.x >> 6);
    if (node >= n) return;
    int lane = threadIdx.x & 63;
    int d0 = lane * 2;
    int hd = lane >> 3;                 // head index for both dims
    float2 q = *(const float2*)&qkv[(size_t)node * 384 + d0];
    float m = -3.0e38f, ssum = 0.f, a0 = 0.f, a1 = 0.f;
    int beg = offs[node], end = offs[node + 1];
    for (int i = beg; i < end; i++) {
        int e = perm[i];
        int s = srcA[e];
        float2 k = *(const float2*)&qkv[(size_t)s * 384 + 128 + d0];
        float p = q.x * k.x + q.y * k.y;
        p += __shfl_xor(p, 1);
        p += __shfl_xor(p, 2);
        p += __shfl_xor(p, 4);
        float score = p * SCALE + eb[(size_t)e * 8 + hd];
        float mn = fmaxf(m, score);
        float sc = __expf(m - mn);
        float a  = __expf(score - mn);
        float2 v = *(const float2*)&qkv[(size_t)s * 384 + 256 + d0];
        ssum = ssum * sc + a;
        a0 = a0 * sc + a * v.x;
        a1 = a1 * sc + a * v.y;
        m = mn;
    }
    float inv = (ssum > 0.f) ? 1.0f / ssum : 0.0f;
    ushort2 ob; ob.x = f2bu(a0 * inv); ob.y = f2bu(a1 * inv);
    *(ushort2*)&attnb[(size_t)node * 128 + d0] = ob;
}

// ------------------------------------------------------------ bf16 MFMA GEMM
// Block = 256 thr = 4 waves; 64 rows x 128 cols per block. Wave w: rows w*16..+15.
// A: bf16 [*, lda]; BT: bf16 [128][K] (row n holds column n of original B).
// Fragment convention (identical for A and BT -> k-permutation cancels):
//   lane l reads 8 contiguous bf16 at row (l&15), k-offset ks + (l>>4)*8.
// C/D (HW-verified): col = lane&15, row = (lane>>4)*4 + reg.
__device__ __forceinline__ void gemm_mfma_body(
    const unsigned short* __restrict__ A, int lda,
    const unsigned short* __restrict__ BT,
    const float* __restrict__ bias,
    const float* __restrict__ res, int ldr,
    float* __restrict__ Cf, int ldc,
    unsigned short* __restrict__ Cb, int ldcb,
    int K, int Mstore, int relu)
{
    const int w   = threadIdx.x >> 6;
    const int l   = threadIdx.x & 63;
    const int c16 = l & 15;
    const int kg  = l >> 4;
    const long arow = (long)blockIdx.x * 64 + w * 16 + c16;
    const unsigned short* Ap = A + arow * lda + kg * 8;
    const unsigned short* Bp = BT + c16 * K + kg * 8;

    f32x4 acc[8];
    #pragma unroll
    for (int i = 0; i < 8; i++) acc[i] = (f32x4){0.f, 0.f, 0.f, 0.f};

    for (int ks = 0; ks < K; ks += 32) {
        short8 a = *(const short8*)(Ap + ks);
        #pragma unroll
        for (int nt = 0; nt < 8; nt++) {
            short8 b = *(const short8*)(Bp + nt * 16 * K + ks);
            acc[nt] = __builtin_amdgcn_mfma_f32_16x16x32_bf16(a, b, acc[nt], 0, 0, 0);
        }
    }

    const long rbase = (long)blockIdx.x * 64 + w * 16 + kg * 4;
    #pragma unroll
    for (int nt = 0; nt < 8; nt++) {
        int col = nt * 16 + c16;
        float bi = bias[col];
        #pragma unroll
        for (int r = 0; r < 4; r++) {
            long grow = rbase + r;
            if (grow >= Mstore) continue;
            float v = acc[nt][r] + bi;
            if (res) v += res[grow * ldr + col];
            if (relu) v = fmaxf(v, 0.f);
            if (Cf) Cf[grow * ldc + col] = v;
            if (Cb) Cb[grow * ldcb + col] = f2bu(v);
        }
    }
}

__global__ __launch_bounds__(256) void gemm_qkv_mfma(
    const unsigned short* __restrict__ A, const unsigned short* __restrict__ WqkvT,
    const float* __restrict__ bq, const float* __restrict__ bk,
    const float* __restrict__ bv, float* __restrict__ qkv)
{
    int sel = blockIdx.y;
    const float* bias = sel == 0 ? bq : sel == 1 ? bk : bv;
    gemm_mfma_body(A, 128, WqkvT + sel * 16384, bias, nullptr, 0,
                   qkv + sel * 128, 384, nullptr, 0, 128, MP, 0);
}

__global__ __launch_bounds__(256) void gemm_ffn1_mfma(
    const unsigned short* __restrict__ A, const unsigned short* __restrict__ W1T,
    const float* __restrict__ b1, unsigned short* __restrict__ midb)
{
    int sel = blockIdx.y;
    gemm_mfma_body(A, 128, W1T + sel * 16384, b1 + sel * 128, nullptr, 0,
                   nullptr, 0, midb + sel * 128, 256, 128, MP, 1);
}

__global__ __launch_bounds__(256) void gemm_mfma_g(
    const unsigned short* __restrict__ A, int lda,
    const unsigned short* __restrict__ BT,
    const float* __restrict__ bias,
    const float* __restrict__ res, int ldr,
    float* __restrict__ Cf, int ldc,
    unsigned short* __restrict__ Cb, int ldcb,
    int K, int Mstore, int relu)
{
    gemm_mfma_body(A, lda, BT, bias, res, ldr, Cf, ldc, Cb, ldcb, K, Mstore, relu);
}

// ---------------------------------------------------------------- launcher
extern "C" void kernel_launch(void* const* d_in, const int* in_sizes, int n_in,
                              void* d_out, int out_size, void* d_ws, size_t ws_size,
                              hipStream_t stream)
{
    (void)in_sizes; (void)n_in; (void)out_size; (void)ws_size;
    const float* h    = (const float*)d_in[0];
    const int*   src  = (const int*)d_in[1];
    const int*   dst  = (const int*)d_in[2];
    const float* ef   = (const float*)d_in[3];
    const float* Wq   = (const float*)d_in[4];
    const float* bq   = (const float*)d_in[5];
    const float* Wk   = (const float*)d_in[6];
    const float* bk   = (const float*)d_in[7];
    const float* Wv   = (const float*)d_in[8];
    const float* bv   = (const float*)d_in[9];
    const float* We   = (const float*)d_in[10];
    const float* be   = (const float*)d_in[11];
    const float* Wo   = (const float*)d_in[12];
    const float* bo   = (const float*)d_in[13];
    const float* g1   = (const float*)d_in[14];
    const float* b1   = (const float*)d_in[15];
    const float* g2   = (const float*)d_in[16];
    const float* b2l  = (const float*)d_in[17];
    const float* W1   = (const float*)d_in[18];
    const float* b1f  = (const float*)d_in[19];
    const float* W2   = (const float*)d_in[20];
    const float* b2f  = (const float*)d_in[21];
    float* out = (float*)d_out;

    char* ws = (char*)d_ws;
    float*          hcf   = (float*)ws;          ws += (size_t)MP * 128 * 4;
    unsigned short* hcb   = (unsigned short*)ws; ws += (size_t)MP * 128 * 2;
    float*          qkv   = (float*)ws;          ws += (size_t)MP * 384 * 4;
    unsigned short* attnb = (unsigned short*)ws; ws += (size_t)MP * 128 * 2;
    float*          eb    = (float*)ws;          ws += (size_t)N_EDGES * 8 * 4;
    int*            offs  = (int*)ws;            ws += ((N_NODES + 1) * 4 + 252) / 256 * 256;
    int*            cnt   = (int*)ws;            ws += ((size_t)N_NODES * 4 + 252) / 256 * 256;
    int*            perm  = (int*)ws;            ws += (size_t)N_EDGES * 4;
    unsigned short* WqkvT = (unsigned short*)ws; ws += 49152 * 2;
    unsigned short* WoT   = (unsigned short*)ws; ws += 16384 * 2;
    unsigned short* W1T   = (unsigned short*)ws; ws += 32768 * 2;
    unsigned short* W2T   = (unsigned short*)ws; ws += 32768 * 2;
    unsigned short* midb  = (unsigned short*)qkv;   // reuse (FFN after hops)
    unsigned short* hnb   = attnb;                  // reuse (LN2 after hops)

    const int rowBlocks = MP / 64;  // 782

    // prologue: LN1 (fp32+bf16), weight prep, edge bias, CSR
    ln_kernel<<<N_NODES / 4, 256, 0, stream>>>(h, g1, b1, hcf, hcb, N_NODES);
    prep_weights<<<512, 256, 0, stream>>>(Wq, Wk, Wv, Wo, W1, W2, WqkvT, WoT, W1T, W2T);
    ebias_kernel<<<2048, 256, 0, stream>>>(ef, We, be, eb, N_EDGES);
    hipMemsetAsync(cnt, 0, N_NODES * 4, stream);
    hist_kernel<<<(N_EDGES + 255) / 256, 256, 0, stream>>>(dst, cnt, N_EDGES);
    scan_kernel<<<1, 1024, 0, stream>>>(cnt, offs, N_NODES);
    hipMemsetAsync(cnt, 0, N_NODES * 4, stream);
    scatter_kernel<<<(N_EDGES + 255) / 256, 256, 0, stream>>>(dst, offs, cnt, perm, N_EDGES);

    // 2 hops
    for (int hop = 0; hop < 2; hop++) {
        gemm_qkv_mfma<<<dim3(rowBlocks, 3), 256, 0, stream>>>(hcb, WqkvT, bq, bk, bv, qkv);
        attn_kernel<<<N_NODES / 4, 256, 0, stream>>>(qkv, eb, offs, perm, src, attnb, N_NODES);
        // hc = hc + attn @ Wo + bo   (in-place residual; writes fp32 + bf16 copies)
        gemm_mfma_g<<<rowBlocks, 256, 0, stream>>>(
            attnb, 128, WoT, bo, hcf, 128, hcf, 128, hcb, 128, 128, MP, 0);
    }

    // FFN
    ln_kernel<<<N_NODES / 4, 256, 0, stream>>>(hcf, g2, b2l, nullptr, hnb, N_NODES);
    gemm_ffn1_mfma<<<dim3(rowBlocks, 2), 256, 0, stream>>>(hnb, W1T, b1f, midb);
    gemm_mfma_g<<<rowBlocks, 256, 0, stream>>>(
        midb, 256, W2T, b2f, hcf, 128, out, 128, nullptr, 0, 256, N_NODES, 0);
}